// Round 2
// baseline (569.126 us; speedup 1.0000x reference)
//
#include <hip/hip_runtime.h>
#include <stdint.h>

#define FP8_MAX 448.0f

typedef float f32x16 __attribute__((ext_vector_type(16)));
typedef int i32x8 __attribute__((ext_vector_type(8)));

// ---------- helpers ----------

// async global->LDS, 16B per lane. LDS dest must be wave-uniform base + lane*16.
__device__ __forceinline__ void async_load16(const void* gptr, void* lptr) {
  __builtin_amdgcn_global_load_lds(
      (const __attribute__((address_space(1))) unsigned int*)(uintptr_t)gptr,
      (__attribute__((address_space(3))) unsigned int*)(unsigned)(uintptr_t)lptr,
      16, 0, 0);
}

// pack 4 fp32 -> 4 fp8 e4m3fn bytes (RNE, OCP on gfx950), byte0 = a
__device__ __forceinline__ unsigned pack4_fp8(float a, float b, float c, float d) {
  int v = __builtin_amdgcn_cvt_pk_fp8_f32(a, b, 0, false);
  v = __builtin_amdgcn_cvt_pk_fp8_f32(c, d, v, true);
  return (unsigned)v;
}

__device__ __forceinline__ float clip_fp8(float q) {
  return fminf(FP8_MAX, fmaxf(-FP8_MAX, q));
}

// assemble a 32-byte A/B fragment from two 16B LDS chunks
__device__ __forceinline__ i32x8 frag32(const unsigned char* rowbase, int o_lo, int o_hi) {
  uint4 lo = *(const uint4*)(rowbase + o_lo);
  uint4 hi = *(const uint4*)(rowbase + o_hi);
  i32x8 f;
  f[0] = lo.x; f[1] = lo.y; f[2] = lo.z; f[3] = lo.w;
  f[4] = hi.x; f[5] = hi.y; f[6] = hi.z; f[7] = hi.w;
  return f;
}

// ---------- pass 1: amax reduction ----------

__global__ void k_amax(const float4* __restrict__ x, long n4, unsigned* __restrict__ out) {
  float m = 0.f;
  const long stride = (long)gridDim.x * blockDim.x;
  for (long i = (long)blockIdx.x * blockDim.x + threadIdx.x; i < n4; i += stride) {
    float4 v = x[i];
    m = fmaxf(m, fmaxf(fmaxf(fabsf(v.x), fabsf(v.y)), fmaxf(fabsf(v.z), fabsf(v.w))));
  }
#pragma unroll
  for (int off = 32; off > 0; off >>= 1)
    m = fmaxf(m, __shfl_xor(m, off, 64));
  __shared__ float sm[4];
  const int wv = threadIdx.x >> 6;
  if ((threadIdx.x & 63) == 0) sm[wv] = m;
  __syncthreads();
  if (threadIdx.x == 0) {
    m = fmaxf(fmaxf(sm[0], sm[1]), fmaxf(sm[2], sm[3]));
    // all values >= 0: uint bit-pattern order == float order
    atomicMax(out, __float_as_uint(m));
  }
}

// ---------- pass 2: quantize x. Unit-stride float4 loads, unit-stride u32 stores ----------

__global__ void k_quant_x(const float4* __restrict__ x, unsigned* __restrict__ q,
                          const unsigned* __restrict__ amax_bits) {
  const float scale = fmaxf(__uint_as_float(*amax_bits), 1e-12f) / 448.0f;
  const long i0 = (long)blockIdx.x * blockDim.x + threadIdx.x;
  const long stride = (long)gridDim.x * blockDim.x;
#pragma unroll
  for (int r = 0; r < 4; r++) {
    const long i = i0 + r * stride;
    float4 v = x[i];
    // true IEEE division to match reference rounding
    q[i] = pack4_fp8(clip_fp8(v.x / scale), clip_fp8(v.y / scale),
                     clip_fp8(v.z / scale), clip_fp8(v.w / scale));
  }
}

// ---------- pass 3: quantize weight (values pre-scaled; just clip+RNE->fp8) ----------

__global__ void k_quant_w(const float4* __restrict__ w, unsigned* __restrict__ q) {
  const long i0 = (long)blockIdx.x * blockDim.x + threadIdx.x;
  const long stride = (long)gridDim.x * blockDim.x;
#pragma unroll
  for (int r = 0; r < 4; r++) {
    const long i = i0 + r * stride;
    float4 v = w[i];
    q[i] = pack4_fp8(clip_fp8(v.x), clip_fp8(v.y), clip_fp8(v.z), clip_fp8(v.w));
  }
}

// ---------- pass 4: fp8 GEMM, 256x256 tile, 8-phase-style pipelined schedule ----------
//
// BM=BN=256, BK=128 fp8 bytes -> tiles are [256 rows][128 B], byte-identical
// geometry to the verified bf16 8-phase template (BK=64 bf16).
// 8 waves (512 thr) as 2(M) x 4(N); wave tile 128x64 = acc[4][2] of 32x32.
// MFMA: mfma_scale_f32_32x32x64_f8f6f4, scales 0x7f (=2^0) -> plain fp8 GEMM.
//
// LDS (128 KiB, full double-buffer):
//   [A buf0 32K][A buf1 32K][B buf0 32K][B buf1 32K]
// Swizzle: 16B chunk slot = chunk ^ (row&7) within each 128B row. Applied on
// the GLOBAL source address during global_load_lds (LDS dest stays linear as
// HW requires) and on LDS offsets during fragment reads. A wave's
// ds_read_b128 then lands 8 lanes per 16B slot = the 1024B/wave floor.
//
// Per K-tile (BK=128): 4 phases, one C-quadrant (2 m-tiles x 1 n-tile x both
// k=64 steps) each: 12x ds_read_b128 + 4x MFMA, wrapped in raw s_barrier
// pairs with setprio(1) around the MFMA cluster (T5). Next tile's 8
// global_load_lds are front-loaded into phases 0-1; the ONLY vmcnt(0) is at
// the iteration boundary, by which point the loads have had >=2 phases
// (~1400 cy) in flight > ~900 cy HBM latency (T3/T4: never drain per phase).
// Correctness: stages only write the idle buffer; iter-end vmcnt(0)+barrier
// is the single hazard point.
//
// A-frag layout (32x32x64): m = lane&31, k = 32*(lane>>5) + byte_idx.
// C/D layout (32x32): col = lane&31, row = (reg&3) + 8*(reg>>2) + 4*(lane>>5).

__global__ __launch_bounds__(512, 2) void k_gemm(
    const unsigned char* __restrict__ qa, const unsigned char* __restrict__ qb,
    const unsigned* __restrict__ amax_bits, const float* __restrict__ wscale,
    const float* __restrict__ bias, float* __restrict__ out,
    int M, int N, int K) {
  __shared__ unsigned char lds[131072];

  const int t = threadIdx.x;
  const int lane = t & 63;
  const int wv = t >> 6;        // 0..7
  const int wm = wv >> 2;       // 0..1  (M dir)
  const int wn = wv & 3;        // 0..3  (N dir)
  const int lr = lane & 31;
  const int h = lane >> 5;      // K-half selector
  const int g = lr & 7;         // row-swizzle key for fragment reads

  // XCD-aware bijective block swizzle (M-major chunks: each XCD keeps 2
  // B-panels L2-resident). 512 blocks % 8 == 0 -> bijective.
  const int nwg = gridDim.x;
  int wg = blockIdx.x;
  if ((nwg & 7) == 0) wg = (wg & 7) * (nwg >> 3) + (wg >> 3);
  const int nby = M >> 8;       // M/256
  const int bx = wg / nby;      // n tile (256 wide)
  const int by = wg - bx * nby; // m tile (256 tall)

  const unsigned char* Ag = qa + (size_t)by * 256 * K;
  const unsigned char* Bg = qb + (size_t)bx * 256 * K;

  // staging: one 128-row unit = 16KB = 512 thr * 2 * 16B. idx -> row=idx>>3,
  // chunk slot cs=idx&7 holds global chunk cs^(row&7). Same formula for A/B.
  size_t gsw[2]; int ldso[2];
#pragma unroll
  for (int r = 0; r < 2; r++) {
    const int idx = t + r * 512;
    const int row = idx >> 3;
    const int cs = idx & 7;
    gsw[r] = (size_t)row * K + (size_t)((cs ^ (row & 7)) << 4);
    ldso[r] = idx << 4;
  }

  // fragment read offsets: global chunk (4*kk + 2h + {0,1}) lives at byte
  // ((4*kk+2h)^g)*16 and that ^16 (since 4kk+2h is even).
  const int cb[2] = { ((2 * h) ^ g) << 4, (((2 * h) | 4) ^ g) << 4 };
  const int a_base = (wm * 128 + lr) * 128;
  const int b_base = (wn * 64 + lr) * 128;

  f32x16 acc[4][2];
#pragma unroll
  for (int i = 0; i < 4; i++)
#pragma unroll
    for (int j = 0; j < 2; j++)
#pragma unroll
      for (int r = 0; r < 16; r++) acc[i][j][r] = 0.f;

  // ---- prologue: stage tile 0 into buf 0 ----
#pragma unroll
  for (int u = 0; u < 2; u++)
#pragma unroll
    for (int r = 0; r < 2; r++) {
      async_load16(Ag + (size_t)u * 128 * K + gsw[r], lds + u * 16384 + ldso[r]);
      async_load16(Bg + (size_t)u * 128 * K + gsw[r], lds + 65536 + u * 16384 + ldso[r]);
    }
  asm volatile("s_waitcnt vmcnt(0)" ::: "memory");
  __builtin_amdgcn_s_barrier();

  const int NT = K >> 7;
  int buf = 0;
  for (int tile = 0; tile < NT; ++tile) {
    const unsigned char* ldsA = lds + buf * 32768;
    const unsigned char* ldsB = lds + 65536 + buf * 32768;
    unsigned char* stA = lds + (buf ^ 1) * 32768;
    unsigned char* stB = lds + 65536 + (buf ^ 1) * 32768;
    const bool have_next = (tile + 1 < NT);
    const size_t kb_next = (size_t)(tile + 1) << 7;

#pragma unroll
    for (int q = 0; q < 4; ++q) {
      const int mp = q >> 1, nj = q & 1;

      // 12x ds_read_b128: A frags for the 2 m-tiles of this quadrant (both
      // k-steps), B frags for this n-tile (both k-steps)
      i32x8 af[2][2], bf[2];
#pragma unroll
      for (int im = 0; im < 2; ++im) {
        const unsigned char* rb = ldsA + a_base + (2 * mp + im) * 4096;
#pragma unroll
        for (int kk = 0; kk < 2; ++kk)
          af[im][kk] = frag32(rb, cb[kk], cb[kk] ^ 16);
      }
      {
        const unsigned char* rb = ldsB + b_base + nj * 4096;
#pragma unroll
        for (int kk = 0; kk < 2; ++kk)
          bf[kk] = frag32(rb, cb[kk], cb[kk] ^ 16);
      }

      // front-loaded prefetch of next tile into the idle buffer:
      // phase 0 -> A (4 loads), phase 1 -> B (4 loads)
      if (q == 0 && have_next) {
#pragma unroll
        for (int u = 0; u < 2; u++)
#pragma unroll
          for (int r = 0; r < 2; r++)
            async_load16(Ag + (size_t)u * 128 * K + gsw[r] + kb_next,
                         stA + u * 16384 + ldso[r]);
      }
      if (q == 1 && have_next) {
#pragma unroll
        for (int u = 0; u < 2; u++)
#pragma unroll
          for (int r = 0; r < 2; r++)
            async_load16(Bg + (size_t)u * 128 * K + gsw[r] + kb_next,
                         stB + u * 16384 + ldso[r]);
      }

      __builtin_amdgcn_s_barrier();
      asm volatile("s_waitcnt lgkmcnt(0)" ::: "memory");
      __builtin_amdgcn_sched_barrier(0);
      __builtin_amdgcn_s_setprio(1);
#pragma unroll
      for (int kk = 0; kk < 2; ++kk)
#pragma unroll
        for (int im = 0; im < 2; ++im)
          acc[2 * mp + im][nj] = __builtin_amdgcn_mfma_scale_f32_32x32x64_f8f6f4(
              af[im][kk], bf[kk], acc[2 * mp + im][nj], 0, 0, 0,
              0x7f7f7f7f, 0, 0x7f7f7f7f);
      __builtin_amdgcn_s_setprio(0);
      __builtin_amdgcn_sched_barrier(0);
      __builtin_amdgcn_s_barrier();
    }

    // iteration boundary: this wave's 8 prefetch loads were issued >=2 phases
    // ago -> drain is ~free. Barrier publishes the new buffer to all waves.
    asm volatile("s_waitcnt vmcnt(0)" ::: "memory");
    __builtin_amdgcn_s_barrier();
    buf ^= 1;
  }

  // ---- epilogue ----
  const float s_comb =
      (fmaxf(__uint_as_float(*amax_bits), 1e-12f) / 448.0f) * wscale[0];
#pragma unroll
  for (int nj = 0; nj < 2; ++nj) {
    const int col = bx * 256 + wn * 64 + nj * 32 + lr;
    const float bv = bias[col];
#pragma unroll
    for (int mi = 0; mi < 4; ++mi) {
      const int row0 = by * 256 + wm * 128 + mi * 32 + 4 * h;
#pragma unroll
      for (int r = 0; r < 16; ++r) {
        const int row = row0 + (r & 3) + 8 * (r >> 2);
        out[(size_t)row * N + col] = acc[mi][nj][r] * s_comb + bv;
      }
    }
  }
}

// ---------- launch ----------

extern "C" void kernel_launch(void* const* d_in, const int* in_sizes, int n_in,
                              void* d_out, int out_size, void* d_ws, size_t ws_size,
                              hipStream_t stream) {
  const float* x = (const float*)d_in[0];        // [B,S,K] fp32
  const float* qw = (const float*)d_in[1];       // [N,K] fp32 (pre-scaled fp8 values)
  const float* wscale = (const float*)d_in[2];   // [1] fp32
  const float* bias = (const float*)d_in[3];     // [N] fp32

  const int N = in_sizes[3];
  const int K = in_sizes[1] / N;
  const int M = in_sizes[0] / K;

  const long nx = (long)M * K;
  const long nw = (long)N * K;

  unsigned char* ws = (unsigned char*)d_ws;
  unsigned* amax_bits = (unsigned*)ws;
  unsigned char* qx8 = ws + 256;
  unsigned char* qw8 = qx8 + nx;

  float* out = (float*)d_out;

  hipMemsetAsync(d_ws, 0, 4, stream);
  k_amax<<<2048, 256, 0, stream>>>((const float4*)x, nx / 4, amax_bits);
  // each thread handles 4 float4s, unit-stride within each pass
  k_quant_x<<<(int)(nx / 4 / 4 / 256), 256, 0, stream>>>(
      (const float4*)x, (unsigned*)qx8, amax_bits);
  k_quant_w<<<(int)(nw / 4 / 4 / 256), 256, 0, stream>>>(
      (const float4*)qw, (unsigned*)qw8);
  const int nwg = (N / 256) * (M / 256);
  k_gemm<<<dim3(nwg), 512, 0, stream>>>(qx8, qw8, amax_bits, wscale, bias, out,
                                        M, N, K);
}

// Round 3
// 443.421 us; speedup vs baseline: 1.2835x; 1.2835x over previous
//
#include <hip/hip_runtime.h>
#include <stdint.h>

#define FP8_MAX 448.0f

typedef float f32x16 __attribute__((ext_vector_type(16)));
typedef int i32x8 __attribute__((ext_vector_type(8)));

// ---------- helpers ----------

// async global->LDS, 16B per lane. LDS dest must be wave-uniform base + lane*16.
__device__ __forceinline__ void async_load16(const void* gptr, void* lptr) {
  __builtin_amdgcn_global_load_lds(
      (const __attribute__((address_space(1))) unsigned int*)(uintptr_t)gptr,
      (__attribute__((address_space(3))) unsigned int*)(unsigned)(uintptr_t)lptr,
      16, 0, 0);
}

// pack 4 fp32 -> 4 fp8 e4m3fn bytes (RNE, OCP on gfx950), byte0 = a
__device__ __forceinline__ unsigned pack4_fp8(float a, float b, float c, float d) {
  int v = __builtin_amdgcn_cvt_pk_fp8_f32(a, b, 0, false);
  v = __builtin_amdgcn_cvt_pk_fp8_f32(c, d, v, true);
  return (unsigned)v;
}

__device__ __forceinline__ float clip_fp8(float q) {
  return fminf(FP8_MAX, fmaxf(-FP8_MAX, q));
}

// assemble a 32-byte A/B fragment from two 16B LDS chunks (o_hi = o_lo ^ 16)
__device__ __forceinline__ i32x8 frag32(const unsigned char* rowbase, int o_lo) {
  uint4 lo = *(const uint4*)(rowbase + o_lo);
  uint4 hi = *(const uint4*)(rowbase + (o_lo ^ 16));
  i32x8 f;
  f[0] = lo.x; f[1] = lo.y; f[2] = lo.z; f[3] = lo.w;
  f[4] = hi.x; f[5] = hi.y; f[6] = hi.z; f[7] = hi.w;
  return f;
}

// ---------- pass 1: amax reduction ----------

__global__ void k_amax(const float4* __restrict__ x, long n4, unsigned* __restrict__ out) {
  float m = 0.f;
  const long stride = (long)gridDim.x * blockDim.x;
  for (long i = (long)blockIdx.x * blockDim.x + threadIdx.x; i < n4; i += stride) {
    float4 v = x[i];
    m = fmaxf(m, fmaxf(fmaxf(fabsf(v.x), fabsf(v.y)), fmaxf(fabsf(v.z), fabsf(v.w))));
  }
#pragma unroll
  for (int off = 32; off > 0; off >>= 1)
    m = fmaxf(m, __shfl_xor(m, off, 64));
  __shared__ float sm[4];
  const int wv = threadIdx.x >> 6;
  if ((threadIdx.x & 63) == 0) sm[wv] = m;
  __syncthreads();
  if (threadIdx.x == 0) {
    m = fmaxf(fmaxf(sm[0], sm[1]), fmaxf(sm[2], sm[3]));
    // all values >= 0: uint bit-pattern order == float order
    atomicMax(out, __float_as_uint(m));
  }
}

// ---------- pass 2: quantize x. Unit-stride float4 loads, unit-stride u32 stores ----------

__global__ void k_quant_x(const float4* __restrict__ x, unsigned* __restrict__ q,
                          const unsigned* __restrict__ amax_bits) {
  const float scale = fmaxf(__uint_as_float(*amax_bits), 1e-12f) / 448.0f;
  const long i0 = (long)blockIdx.x * blockDim.x + threadIdx.x;
  const long stride = (long)gridDim.x * blockDim.x;
#pragma unroll
  for (int r = 0; r < 4; r++) {
    const long i = i0 + r * stride;
    float4 v = x[i];
    // true IEEE division to match reference rounding
    q[i] = pack4_fp8(clip_fp8(v.x / scale), clip_fp8(v.y / scale),
                     clip_fp8(v.z / scale), clip_fp8(v.w / scale));
  }
}

// ---------- pass 3: quantize weight (values pre-scaled; just clip+RNE->fp8) ----------

__global__ void k_quant_w(const float4* __restrict__ w, unsigned* __restrict__ q) {
  const long i0 = (long)blockIdx.x * blockDim.x + threadIdx.x;
  const long stride = (long)gridDim.x * blockDim.x;
#pragma unroll
  for (int r = 0; r < 4; r++) {
    const long i = i0 + r * stride;
    float4 v = w[i];
    q[i] = pack4_fp8(clip_fp8(v.x), clip_fp8(v.y), clip_fp8(v.z), clip_fp8(v.w));
  }
}

// ---------- pass 4: fp8 GEMM, 256x256 tile, BK=64, triple-buffered counted pipeline ----
//
// 8 waves (512 thr) as 2(M) x 4(N); wave tile 128x64 = acc[4][2] of 32x32.
// MFMA: mfma_scale_f32_32x32x64_f8f6f4, scales 0x7f (=2^0) -> plain fp8 GEMM at
// 2x the non-scaled rate.
//
// LDS 96 KiB: A[3 bufs x 16KB] @0, B[3 bufs x 16KB] @49152. TRIPLE buffer:
// tile t reads buf[t%3]; loads for t+2 issue during tile t. Boundary wait is a
// COUNTED s_waitcnt vmcnt(4): keep the 4 newest loads (tile t+2's) in flight,
// wait only for tile t+1's, which were issued two tiles (~4 phases) ago ->
// HBM latency fully amortized (T3/T4; m218: counted-vs-drain0 = +38..73%).
//
// Zero-redundancy reads: per tile per wave 12x ds_read_b128 (A 8, B 4), 8 MFMA.
// Phase 0: read af[0..1]+bf[0..1], stage A(t+2), bar, lgkm0, 4 MFMA, bar.
// Phase 1: read af[2..3] (bf persists in regs), stage B(t+2), bar, lgkm0,
//          4 MFMA, vmcnt(4), bar.
//
// Swizzle (64B rows, 4x16B chunks): slot = chunk ^ ((row>>1)&3), applied on the
// GLOBAL source during global_load_lds (LDS dest linear as HW requires) and on
// LDS offsets at read time. Each 8-lane read group then covers all 8 bank-quads
// bijectively. (Round-2 lesson: ~4 conflict-cy/b128 is the m134 baseline cost,
// not a fixable pathology.)
//
// Write-hazard audit: stage at tile t targets buf[(t+2)%3]; the only prior
// reader is tile t-1, whose reads are lgkm-drained before the end-of-(t-1)
// barrier, which precedes tile t's stage issues. Reads of tile t+1 wait on the
// boundary vmcnt(4) which covers t+1's loads. Single hazard point per tile.
//
// A-frag layout (32x32x64): m = lane&31, k = 32*(lane>>5) + byte_idx.
// C/D layout (32x32): col = lane&31, row = (reg&3) + 8*(reg>>2) + 4*(lane>>5).

__global__ __launch_bounds__(512, 2) void k_gemm(
    const unsigned char* __restrict__ qa, const unsigned char* __restrict__ qb,
    const unsigned* __restrict__ amax_bits, const float* __restrict__ wscale,
    const float* __restrict__ bias, float* __restrict__ out,
    int M, int N, int K) {
  __shared__ unsigned char lds[98304];

  const int t = threadIdx.x;
  const int lane = t & 63;
  const int wv = t >> 6;        // 0..7
  const int wm = wv >> 2;       // 0..1  (M dir)
  const int wn = wv & 3;        // 0..3  (N dir)
  const int lr = lane & 31;
  const int h = lane >> 5;      // K-half selector
  const int key = (lr >> 1) & 3;

  // plain 2D grid: bx (n) fastest -> round-robin over XCDs keeps 2 B-panels
  // per XCD L2-resident; L3 absorbs cross-XCD A re-reads (round-0 behavior).
  const int bx = blockIdx.x;    // n tile (256 wide)
  const int by = blockIdx.y;    // m tile (256 tall)

  const unsigned char* Ag = qa + (size_t)by * 256 * K;
  const unsigned char* Bg = qb + (size_t)bx * 256 * K;

  // staging: one tile = 16KB = 1024 chunks; 512 thr x 2. idx -> row=idx>>2,
  // chunk slot cs=idx&3 holds global chunk cs^((row>>1)&3).
  size_t g_off[2]; int l_off[2];
#pragma unroll
  for (int r = 0; r < 2; r++) {
    const int idx = t + r * 512;
    const int row = idx >> 2;
    const int cs = idx & 3;
    g_off[r] = (size_t)row * K + (size_t)((cs ^ ((row >> 1) & 3)) << 4);
    l_off[r] = idx << 4;
  }

  // fragment read: lane's 32B = chunks {2h, 2h+1} of its row, at swizzled slots
  const int o_lo = ((2 * h) ^ key) << 4;  // partner chunk at o_lo ^ 16
  const int a_rowoff = (wm * 128 + lr) * 64;  // + im*2048 per m-subtile
  const int b_rowoff = (wn * 64 + lr) * 64;   // + nj*2048 per n-subtile

  f32x16 acc[4][2];
#pragma unroll
  for (int i = 0; i < 4; i++)
#pragma unroll
    for (int j = 0; j < 2; j++)
#pragma unroll
      for (int r = 0; r < 16; r++) acc[i][j][r] = 0.f;

  // rotating buffer bases: read a0/b0, prefetch into a2/b2
  int a0 = 0, a1 = 16384, a2 = 32768;
  int b0 = 49152, b1 = 65536, b2 = 81920;

  // ---- prologue: stage tiles 0 and 1 ----
#pragma unroll
  for (int r = 0; r < 2; r++) {
    async_load16(Ag + g_off[r], lds + a0 + l_off[r]);
    async_load16(Bg + g_off[r], lds + b0 + l_off[r]);
  }
#pragma unroll
  for (int r = 0; r < 2; r++) {
    async_load16(Ag + g_off[r] + 64, lds + a1 + l_off[r]);
    async_load16(Bg + g_off[r] + 64, lds + b1 + l_off[r]);
  }
  asm volatile("s_waitcnt vmcnt(4)" ::: "memory");  // tile 0 landed; tile 1 in flight
  __builtin_amdgcn_s_barrier();

  const int NT = K >> 6;
  for (int tile = 0; tile < NT; ++tile) {
    const bool haveS = (tile + 2 < NT);
    const size_t kb2 = (size_t)(tile + 2) << 6;
    const unsigned char* pa = lds + a0 + a_rowoff;
    const unsigned char* pb = lds + b0 + b_rowoff;

    // ---- phase 0: af[0..1], bf[0..1]; stage A(t+2); 4 MFMA ----
    i32x8 af0 = frag32(pa, o_lo);
    i32x8 af1 = frag32(pa + 2048, o_lo);
    i32x8 bf0 = frag32(pb, o_lo);
    i32x8 bf1 = frag32(pb + 2048, o_lo);
    if (haveS) {
#pragma unroll
      for (int r = 0; r < 2; r++)
        async_load16(Ag + g_off[r] + kb2, lds + a2 + l_off[r]);
    }
    __builtin_amdgcn_s_barrier();
    asm volatile("s_waitcnt lgkmcnt(0)" ::: "memory");
    __builtin_amdgcn_sched_barrier(0);
    __builtin_amdgcn_s_setprio(1);
    acc[0][0] = __builtin_amdgcn_mfma_scale_f32_32x32x64_f8f6f4(
        af0, bf0, acc[0][0], 0, 0, 0, 0x7f7f7f7f, 0, 0x7f7f7f7f);
    acc[0][1] = __builtin_amdgcn_mfma_scale_f32_32x32x64_f8f6f4(
        af0, bf1, acc[0][1], 0, 0, 0, 0x7f7f7f7f, 0, 0x7f7f7f7f);
    acc[1][0] = __builtin_amdgcn_mfma_scale_f32_32x32x64_f8f6f4(
        af1, bf0, acc[1][0], 0, 0, 0, 0x7f7f7f7f, 0, 0x7f7f7f7f);
    acc[1][1] = __builtin_amdgcn_mfma_scale_f32_32x32x64_f8f6f4(
        af1, bf1, acc[1][1], 0, 0, 0, 0x7f7f7f7f, 0, 0x7f7f7f7f);
    __builtin_amdgcn_s_setprio(0);
    __builtin_amdgcn_sched_barrier(0);
    __builtin_amdgcn_s_barrier();

    // ---- phase 1: af[2..3] (bf persists); stage B(t+2); 4 MFMA ----
    i32x8 af2 = frag32(pa + 4096, o_lo);
    i32x8 af3 = frag32(pa + 6144, o_lo);
    if (haveS) {
#pragma unroll
      for (int r = 0; r < 2; r++)
        async_load16(Bg + g_off[r] + kb2, lds + b2 + l_off[r]);
    }
    __builtin_amdgcn_s_barrier();
    asm volatile("s_waitcnt lgkmcnt(0)" ::: "memory");
    __builtin_amdgcn_sched_barrier(0);
    __builtin_amdgcn_s_setprio(1);
    acc[2][0] = __builtin_amdgcn_mfma_scale_f32_32x32x64_f8f6f4(
        af2, bf0, acc[2][0], 0, 0, 0, 0x7f7f7f7f, 0, 0x7f7f7f7f);
    acc[2][1] = __builtin_amdgcn_mfma_scale_f32_32x32x64_f8f6f4(
        af2, bf1, acc[2][1], 0, 0, 0, 0x7f7f7f7f, 0, 0x7f7f7f7f);
    acc[3][0] = __builtin_amdgcn_mfma_scale_f32_32x32x64_f8f6f4(
        af3, bf0, acc[3][0], 0, 0, 0, 0x7f7f7f7f, 0, 0x7f7f7f7f);
    acc[3][1] = __builtin_amdgcn_mfma_scale_f32_32x32x64_f8f6f4(
        af3, bf1, acc[3][1], 0, 0, 0, 0x7f7f7f7f, 0, 0x7f7f7f7f);
    __builtin_amdgcn_s_setprio(0);
    __builtin_amdgcn_sched_barrier(0);

    // ---- boundary: counted wait (tile t+1's loads landed; t+2's may fly) ----
    if (haveS) {
      asm volatile("s_waitcnt vmcnt(4)" ::: "memory");
    } else {
      asm volatile("s_waitcnt vmcnt(0)" ::: "memory");
    }
    __builtin_amdgcn_s_barrier();

    // rotate buffers
    int ta = a0; a0 = a1; a1 = a2; a2 = ta;
    int tb = b0; b0 = b1; b1 = b2; b2 = tb;
  }

  // ---- epilogue ----
  const float s_comb =
      (fmaxf(__uint_as_float(*amax_bits), 1e-12f) / 448.0f) * wscale[0];
#pragma unroll
  for (int nj = 0; nj < 2; ++nj) {
    const int col = bx * 256 + wn * 64 + nj * 32 + lr;
    const float bv = bias[col];
#pragma unroll
    for (int mi = 0; mi < 4; ++mi) {
      const int row0 = by * 256 + wm * 128 + mi * 32 + 4 * h;
#pragma unroll
      for (int r = 0; r < 16; ++r) {
        const int row = row0 + (r & 3) + 8 * (r >> 2);
        out[(size_t)row * N + col] = acc[mi][nj][r] * s_comb + bv;
      }
    }
  }
}

// ---------- launch ----------

extern "C" void kernel_launch(void* const* d_in, const int* in_sizes, int n_in,
                              void* d_out, int out_size, void* d_ws, size_t ws_size,
                              hipStream_t stream) {
  const float* x = (const float*)d_in[0];        // [B,S,K] fp32
  const float* qw = (const float*)d_in[1];       // [N,K] fp32 (pre-scaled fp8 values)
  const float* wscale = (const float*)d_in[2];   // [1] fp32
  const float* bias = (const float*)d_in[3];     // [N] fp32

  const int N = in_sizes[3];
  const int K = in_sizes[1] / N;
  const int M = in_sizes[0] / K;

  const long nx = (long)M * K;
  const long nw = (long)N * K;

  unsigned char* ws = (unsigned char*)d_ws;
  unsigned* amax_bits = (unsigned*)ws;
  unsigned char* qx8 = ws + 256;
  unsigned char* qw8 = qx8 + nx;

  float* out = (float*)d_out;

  hipMemsetAsync(d_ws, 0, 4, stream);
  k_amax<<<2048, 256, 0, stream>>>((const float4*)x, nx / 4, amax_bits);
  // each thread handles 4 float4s, unit-stride within each pass
  k_quant_x<<<(int)(nx / 4 / 4 / 256), 256, 0, stream>>>(
      (const float4*)x, (unsigned*)qx8, amax_bits);
  k_quant_w<<<(int)(nw / 4 / 4 / 256), 256, 0, stream>>>(
      (const float4*)qw, (unsigned*)qw8);
  dim3 grid(N / 256, M / 256);
  k_gemm<<<grid, 512, 0, stream>>>(qx8, qw8, amax_bits, wscale, bias, out,
                                   M, N, K);
}